// Round 10
// baseline (797.237 us; speedup 1.0000x reference)
//
#include <hip/hip_runtime.h>
#include <hip/hip_bf16.h>
#include <hip/hip_fp8.h>
#include <math.h>

typedef __bf16 bf16x8 __attribute__((ext_vector_type(8)));
typedef float f32x4 __attribute__((ext_vector_type(4)));
typedef unsigned short u16x4 __attribute__((ext_vector_type(4)));
typedef unsigned char u8;

#define AS1P const __attribute__((address_space(1))) void*
#define AS3P __attribute__((address_space(3))) void*

__device__ __forceinline__ float b2f(unsigned short h) {
    unsigned int u = ((unsigned int)h) << 16;
    return __builtin_bit_cast(float, u);
}
__device__ __forceinline__ unsigned short f2b(float f) {
    unsigned int u = __builtin_bit_cast(unsigned int, f);
    u += 0x7FFFu + ((u >> 16) & 1u);
    return (unsigned short)(u >> 16);
}
__device__ __forceinline__ u8 f2e(float x) {
    __hip_fp8_e4m3 h(x);
    return (u8)h.__x;
}
__device__ __forceinline__ float silu(float c) {
    return c * __builtin_amdgcn_rcpf(1.0f + __expf(-c));
}

// ---------------- tiled transpose + fp8 convert (scale folded): dst[C][R] fp8
__global__ __launch_bounds__(256) void k_convT8(const float* __restrict__ src,
                                                u8* __restrict__ dst,
                                                int R, int C, float scale) {
    __shared__ float tile[32][33];
    int tx = threadIdx.x, ty = threadIdx.y;
    int r0 = blockIdx.y << 5, c0 = blockIdx.x << 5;
#pragma unroll
    for (int i = 0; i < 4; ++i)
        tile[ty + 8 * i][tx] = src[(long long)(r0 + ty + 8 * i) * C + c0 + tx];
    __syncthreads();
#pragma unroll
    for (int i = 0; i < 4; ++i)
        dst[(long long)(c0 + ty + 8 * i) * R + r0 + tx] = f2e(tile[tx][ty + 8 * i] * scale);
}

// ---------------- LayerNorm -> fp8 xn
__global__ __launch_bounds__(256) void k_ln(const float* __restrict__ x,
                                            const float* __restrict__ g,
                                            const float* __restrict__ b,
                                            u8* __restrict__ xn) {
    int row = blockIdx.x;
    int t = threadIdx.x;
    const float* xr = x + (long long)row * 768;
    float v0 = xr[t], v1 = xr[t + 256], v2 = xr[t + 512];
    float s = v0 + v1 + v2;
    float q = v0 * v0 + v1 * v1 + v2 * v2;
#pragma unroll
    for (int off = 32; off > 0; off >>= 1) {
        s += __shfl_xor(s, off);
        q += __shfl_xor(q, off);
    }
    __shared__ float ss[4], sq[4];
    int w = t >> 6;
    if ((t & 63) == 0) { ss[w] = s; sq[w] = q; }
    __syncthreads();
    float S_ = ss[0] + ss[1] + ss[2] + ss[3];
    float Q_ = sq[0] + sq[1] + sq[2] + sq[3];
    float mu = S_ * (1.0f / 768.0f);
    float var = Q_ * (1.0f / 768.0f) - mu * mu;
    float rs = rsqrtf(var + 1e-5f);
    u8* xo = xn + (long long)row * 768;
    xo[t]       = f2e((v0 - mu) * rs * g[t]       + b[t]);
    xo[t + 256] = f2e((v1 - mu) * rs * g[t + 256] + b[t + 256]);
    xo[t + 512] = f2e((v2 - mu) * rs * g[t + 512] + b[t + 512]);
}

// ---------------- RoPE + per-head affine (bS bf16 -> q,k bf16)
__global__ __launch_bounds__(128) void k_rope(const unsigned short* __restrict__ bS,
                                              const float* __restrict__ gqk,
                                              const float* __restrict__ bqk,
                                              unsigned short* __restrict__ q,
                                              unsigned short* __restrict__ k) {
    int row = blockIdx.x;
    int l = row & 511;
    int s = threadIdx.x;
    int j = s & 63;
    int partner = s ^ 64;
    float b0 = b2f(bS[(long long)row * 128 + s]);
    float bp = b2f(bS[(long long)row * 128 + partner]);
    float invf = __expf((float)j * -0.14391156831f);
    float th = (float)l * invf;
    float sn, cs;
    __sincosf(th, &sn, &cs);
    float sign = (s < 64) ? -1.0f : 1.0f;
    float preq  = b0 * gqk[s]           + bqk[s];
    float preqp = bp * gqk[partner]     + bqk[partner];
    q[(long long)row * 128 + s] = f2b(preq * cs + sign * preqp * sn);
    float prek  = b0 * gqk[128 + s]       + bqk[128 + s];
    float prekp = bp * gqk[128 + partner] + bqk[128 + partner];
    k[(long long)row * 128 + s] = f2b(prek * cs + sign * prekp * sn);
}

// ================= 128^2 bf16 kernel (QK only: P = relu^2(qk/L + bias))
__global__ __launch_bounds__(256) void k_qk(const unsigned short* __restrict__ A,
                                            const unsigned short* __restrict__ B,
                                            const float* __restrict__ wrel,
                                            unsigned short* __restrict__ P) {
    __shared__ __align__(16) unsigned short As[128 * 64];
    __shared__ __align__(16) unsigned short Bs[128 * 64];
    int t = threadIdx.x;
    int w = t >> 6, lane = t & 63;
    int wr = w >> 1, wc = w & 1;
    int bx = blockIdx.x, by = blockIdx.y, bz = blockIdx.z;
    const unsigned short* Ab = A + (long long)bz * 512 * 128 + (long long)by * 128 * 128;
    const unsigned short* Bb = B + (long long)bz * 512 * 128 + (long long)bx * 128 * 128;

    f32x4 acc[4][4];
#pragma unroll
    for (int m = 0; m < 4; ++m)
#pragma unroll
        for (int n = 0; n < 4; ++n) acc[m][n] = (f32x4){0.f, 0.f, 0.f, 0.f};

    int rowA = (w << 3) + (lane >> 3);
    int colA = (lane & 7) << 3;

    for (int k0 = 0; k0 < 128; k0 += 64) {
#pragma unroll
        for (int i = 0; i < 4; ++i) {
            int r = (i << 5) + rowA;
            __builtin_amdgcn_global_load_lds(
                (AS1P)(Ab + (long long)r * 128 + k0 + colA),
                (AS3P)(&As[(i << 11) + (w << 9)]), 16, 0, 0);
            __builtin_amdgcn_global_load_lds(
                (AS1P)(Bb + (long long)r * 128 + k0 + colA),
                (AS3P)(&Bs[(i << 11) + (w << 9)]), 16, 0, 0);
        }
        __syncthreads();
#pragma unroll
        for (int ks = 0; ks < 2; ++ks) {
            bf16x8 af[4], bfr[4];
#pragma unroll
            for (int m = 0; m < 4; ++m)
                af[m] = *(const bf16x8*)&As[((wr << 6) + (m << 4) + (lane & 15)) * 64 +
                                            (ks << 5) + ((lane >> 4) << 3)];
#pragma unroll
            for (int n = 0; n < 4; ++n)
                bfr[n] = *(const bf16x8*)&Bs[((wc << 6) + (n << 4) + (lane & 15)) * 64 +
                                             (ks << 5) + ((lane >> 4) << 3)];
#pragma unroll
            for (int m = 0; m < 4; ++m)
#pragma unroll
                for (int n = 0; n < 4; ++n)
                    acc[m][n] = __builtin_amdgcn_mfma_f32_16x16x32_bf16(bfr[n], af[m],
                                                                        acc[m][n], 0, 0, 0);
        }
        __syncthreads();
    }

    int c15 = lane & 15, qq = lane >> 4;
    int rowb = (by << 7) + (wr << 6) + c15;
    int colb = (bx << 7) + (wc << 6) + (qq << 2);
#pragma unroll
    for (int m = 0; m < 4; ++m) {
#pragma unroll
        for (int n = 0; n < 4; ++n) {
            int grow = rowb + (m << 4);
            int gcol = colb + (n << 4);
            f32x4 a = acc[m][n];
            int base = gcol - grow + 511;
            u16x4 o;
#pragma unroll
            for (int i = 0; i < 4; ++i) {
                float val = a[i] * (1.0f / 512.0f) + wrel[base + i];
                val = fmaxf(val, 0.0f);
                o[i] = f2b(val * val);
            }
            *(u16x4*)(P + ((long long)(bz * 512 + grow)) * 512 + gcol) = o;
        }
    }
}

// ================= PV bf16 (R8 ledger kernel, EPI2 only): gated -> fp8 x8
__device__ __forceinline__ bf16x8 ldsb(const char* p) {
    bf16x8 r;
    unsigned int off =
        (unsigned int)(unsigned long long)(__attribute__((address_space(3))) const void*)p;
    asm volatile("ds_read_b128 %0, %1" : "=v"(r) : "v"(off));
    return r;
}
__device__ __forceinline__ void stage64(const unsigned short* __restrict__ g, int ldk,
                                        char* lds, int r0, int w, int lane) {
    int row = r0 + (w << 3) + (lane >> 3);
    int colb = (lane & 7) << 4;
    int scolb = colb ^ ((row & 7) << 4);
    __builtin_amdgcn_global_load_lds(
        (AS1P)((const char*)g + (long long)row * (ldk * 2) + scolb),
        (AS3P)(lds + (r0 << 7) + (w << 10)), 16, 0, 0);
}

template <int NT>
__global__ __launch_bounds__(512, 2) void k_pv(const unsigned short* __restrict__ A,
                                               const unsigned short* __restrict__ B,
                                               long long strideA, long long strideB,
                                               u8* __restrict__ gated8,
                                               const unsigned short* __restrict__ u) {
    constexpr int K = NT * 64;
    __shared__ __align__(16) char As[2][256 * 128];
    __shared__ __align__(16) char Bs[2][256 * 128];
    int tid = threadIdx.x;
    int w = tid >> 6, lane = tid & 63;
    int wr = w >> 2, wc = w & 3;
    int c15 = lane & 15, qq = lane >> 4;
    int g = (c15 & 7) << 4;
    int o0 = c15 * 128 + ((qq * 16) ^ g);
    int o1 = c15 * 128 + ((64 + qq * 16) ^ g);
    int bx = blockIdx.x, by = blockIdx.y, bz = blockIdx.z;
    const unsigned short* Ab = A + bz * strideA + (long long)by * 256 * K;
    const unsigned short* Bb = B + bz * strideB + (long long)bx * 256 * K;

    f32x4 acc[8][4];
#pragma unroll
    for (int m = 0; m < 8; ++m)
#pragma unroll
        for (int n = 0; n < 4; ++n) acc[m][n] = (f32x4){0.f, 0.f, 0.f, 0.f};

    const int abase = wr * 16384;
    const int bbase = wc * 8192;
    char* A0 = As[0];
    char* A1 = As[1];
    char* B0 = Bs[0];
    char* B1 = Bs[1];
    bf16x8 afA[2], afB[2], bfrA[4], bfrB[4];

#define STAGE(gA, gB, bufA, bufB)                          \
    stage64(gA, K, bufA, 0, w, lane);                      \
    stage64(gA, K, bufA, 64, w, lane);                     \
    stage64(gA, K, bufA, 128, w, lane);                    \
    stage64(gA, K, bufA, 192, w, lane);                    \
    stage64(gB, K, bufB, 0, w, lane);                      \
    stage64(gB, K, bufB, 64, w, lane);                     \
    stage64(gB, K, bufB, 128, w, lane);                    \
    stage64(gB, K, bufB, 192, w, lane);
#define LA(DST, mp, OKS, BUF)                              \
    DST[0] = ldsb((BUF) + abase + (mp) * 4096 + (OKS));    \
    DST[1] = ldsb((BUF) + abase + (mp) * 4096 + 2048 + (OKS));
#define LB(DST, OKS, BUF)                                  \
    DST[0] = ldsb((BUF) + bbase + (OKS));                  \
    DST[1] = ldsb((BUF) + bbase + 2048 + (OKS));           \
    DST[2] = ldsb((BUF) + bbase + 4096 + (OKS));           \
    DST[3] = ldsb((BUF) + bbase + 6144 + (OKS));
#define WAITL(N)                                           \
    asm volatile("s_waitcnt lgkmcnt(" #N ")" ::: "memory");\
    __builtin_amdgcn_sched_barrier(0);
#define MM(mp, BFR, AF)                                                               \
    __builtin_amdgcn_s_setprio(1);                                                    \
    _Pragma("unroll") for (int j_ = 0; j_ < 2; ++j_)                                  \
        _Pragma("unroll") for (int n_ = 0; n_ < 4; ++n_)                              \
            acc[(mp) * 2 + j_][n_] = __builtin_amdgcn_mfma_f32_16x16x32_bf16(         \
                BFR[n_], AF[j_], acc[(mp) * 2 + j_][n_], 0, 0, 0);                    \
    __builtin_amdgcn_s_setprio(0);
#define TILE(CA, CB, NA, NB, t)                                                       \
    LA(afB, 1, o0, CA) WAITL(2) MM(0, bfrA, afA)                                      \
    LA(afA, 2, o0, CA) WAITL(2) MM(1, bfrA, afB)                                      \
    LA(afB, 3, o0, CA) LB(bfrB, o1, CB) WAITL(6) MM(2, bfrA, afA)                     \
    LA(afA, 0, o1, CA) WAITL(6) MM(3, bfrA, afB)                                      \
    LA(afB, 1, o1, CA) WAITL(2) MM(0, bfrB, afA)                                      \
    LA(afA, 2, o1, CA) WAITL(2) MM(1, bfrB, afB)                                      \
    LA(afB, 3, o1, CA) WAITL(2) MM(2, bfrB, afA)                                      \
    WAITL(0) MM(3, bfrB, afB)                                                         \
    __builtin_amdgcn_s_barrier();                                                     \
    if ((t) + 2 < NT) {                                                               \
        STAGE(Ab + ((t) + 2) * 64, Bb + ((t) + 2) * 64, CA, CB)                       \
        asm volatile("s_waitcnt vmcnt(8)" ::: "memory");                              \
    } else if ((t) + 1 < NT) {                                                        \
        asm volatile("s_waitcnt vmcnt(0)" ::: "memory");                              \
    }                                                                                 \
    __builtin_amdgcn_sched_barrier(0);                                                \
    if ((t) + 1 < NT) { LB(bfrA, o0, NB) LA(afA, 0, o0, NA) }

    STAGE(Ab, Bb, A0, B0)
    STAGE(Ab + 64, Bb + 64, A1, B1)
    asm volatile("s_waitcnt vmcnt(8)" ::: "memory");
    __builtin_amdgcn_s_barrier();
    LB(bfrA, o0, B0) LA(afA, 0, o0, A0)

#pragma unroll 1
    for (int t = 0; t < NT; t += 2) {
        TILE(A0, B0, A1, B1, t)
        TILE(A1, B1, A0, B0, t + 1)
    }
#undef STAGE
#undef LA
#undef LB
#undef WAITL
#undef MM
#undef TILE

    int rowb = by * 256 + wr * 128 + c15;
    int colb = bx * 256 + wc * 64 + (qq << 2);
#pragma unroll
    for (int m = 0; m < 8; ++m) {
#pragma unroll
        for (int n = 0; n < 4; ++n) {
            int R = rowb + m * 16;
            int C = colb + n * 16;
            f32x4 a = acc[m][n];
            long long idx = ((long long)(bz * 512 + R)) * 1536 + C;
            u16x4 uu = *(const u16x4*)(u + idx);
            unsigned int pk = 0;
#pragma unroll
            for (int i = 0; i < 4; ++i)
                pk |= ((unsigned int)f2e(a[i] * b2f(uu[i]) * 8.0f)) << (8 * i);
            *(unsigned int*)(gated8 + idx) = pk;
        }
    }
}

// ================= 256x256 fp8 kernel: BK=128 (128B rows), 2-slot dbuf (128KB),
// counted vmcnt(8) + counted-lgkm ks-pipeline, XOR-16B granule swizzle (free).
__device__ __forceinline__ long ldsb64(const char* p) {
    long r;
    unsigned int off =
        (unsigned int)(unsigned long long)(__attribute__((address_space(3))) const void*)p;
    asm volatile("ds_read_b64 %0, %1" : "=v"(r) : "v"(off));
    return r;
}
__device__ __forceinline__ const char* fraddr(const char* T, int row, int ks, int qq) {
    int offs = ks * 32 + qq * 8;
    int gg = offs >> 4, wb = offs & 8;
    return T + row * 128 + (((gg ^ (row & 7)) << 4) | wb);
}
// stage 256x128B fp8 tile (32KB): 512 thr x 4 issues, linear dest, pre-swz src
template <int K>
__device__ __forceinline__ void stageF(const u8* __restrict__ g, char* lds, int tid) {
#pragma unroll
    for (int i = 0; i < 4; ++i) {
        int ch = i * 512 + tid;
        int row = ch >> 3;
        int gg = ch & 7;
        __builtin_amdgcn_global_load_lds(
            (AS1P)(g + (long long)row * K + ((gg ^ (row & 7)) << 4)),
            (AS3P)(lds + ch * 16), 16, 0, 0);
    }
}

// EPI: 10 = UV (u bx<6 | vT bx6-11 | bS bx==12, scale 1/32)
//      3  = out f32 (+o_b+x, scale 1/256)
template <int EPI, bool SWZ, int NT>
__global__ __launch_bounds__(512) void kF(const u8* __restrict__ A,
                                          const u8* __restrict__ B,
                                          void* p0, void* p1, void* p2,
                                          const void* p3) {
    constexpr int K = NT * 128;
    __shared__ __align__(16) char As[2][256 * 128];
    __shared__ __align__(16) char Bs[2][256 * 128];
    int tid = threadIdx.x;
    int w = tid >> 6, lane = tid & 63;
    int wr = w >> 2, wc = w & 3;
    int c15 = lane & 15, qq = lane >> 4;
    int bx = blockIdx.x, by = blockIdx.y;
    if constexpr (SWZ) {
        int gx = gridDim.x;
        int nb = gx * gridDim.y;
        int bid = by * gx + bx;
        int s = (bid & 7) * (nb >> 3) + (bid >> 3);
        bx = s % gx;
        by = s / gx;
    }
    const u8* Ab = A + (long long)by * 256 * K;
    const u8* Bb = B + (long long)bx * 256 * K;

    f32x4 acc[8][4];
#pragma unroll
    for (int m = 0; m < 8; ++m)
#pragma unroll
        for (int n = 0; n < 4; ++n) acc[m][n] = (f32x4){0.f, 0.f, 0.f, 0.f};

    const bool swapped = (EPI != 10) || !(bx >= 6 && bx < 12);

#define RDF(AF, BF, ks)                                                      \
    _Pragma("unroll") for (int n_ = 0; n_ < 4; ++n_)                         \
        BF[n_] = ldsb64(fraddr(Bt, wc * 64 + n_ * 16 + c15, ks, qq));        \
    _Pragma("unroll") for (int m_ = 0; m_ < 8; ++m_)                         \
        AF[m_] = ldsb64(fraddr(At, wr * 128 + m_ * 16 + c15, ks, qq));
#define WAITLF(N)                                                            \
    asm volatile("s_waitcnt lgkmcnt(" #N ")" ::: "memory");                  \
    __builtin_amdgcn_sched_barrier(0);
#define MMF(AF, BF)                                                          \
    __builtin_amdgcn_s_setprio(1);                                           \
    _Pragma("unroll") for (int m_ = 0; m_ < 8; ++m_)                         \
        _Pragma("unroll") for (int n_ = 0; n_ < 4; ++n_) {                   \
            if (swapped)                                                     \
                acc[m_][n_] = __builtin_amdgcn_mfma_f32_16x16x32_fp8_fp8(    \
                    BF[n_], AF[m_], acc[m_][n_], 0, 0, 0);                   \
            else                                                             \
                acc[m_][n_] = __builtin_amdgcn_mfma_f32_16x16x32_fp8_fp8(    \
                    AF[m_], BF[n_], acc[m_][n_], 0, 0, 0);                   \
        }                                                                    \
    __builtin_amdgcn_s_setprio(0);

    // prologue: tiles 0,1
    stageF<K>(Ab, As[0], tid);
    stageF<K>(Bb, Bs[0], tid);
    stageF<K>(Ab + 128, As[1], tid);
    stageF<K>(Bb + 128, Bs[1], tid);

#pragma unroll 1
    for (int t = 0; t < NT; ++t) {
        if (t < NT - 1)
            asm volatile("s_waitcnt vmcnt(8)" ::: "memory");
        else
            asm volatile("s_waitcnt vmcnt(0)" ::: "memory");
        __builtin_amdgcn_s_barrier();
        __builtin_amdgcn_sched_barrier(0);
        const char* At = As[t & 1];
        const char* Bt = Bs[t & 1];
        long af[8], bfv[4], af2[8], bfv2[4];
        RDF(af, bfv, 0)
        RDF(af2, bfv2, 1)
        WAITLF(12)
        MMF(af, bfv)
        RDF(af, bfv, 2)
        WAITLF(12)
        MMF(af2, bfv2)
        RDF(af2, bfv2, 3)
        WAITLF(12)
        MMF(af, bfv)
        WAITLF(0)
        __builtin_amdgcn_s_barrier();  // all waves done reading slot t&1
        if (t + 2 < NT) {
            stageF<K>(Ab + (long long)(t + 2) * 128, As[t & 1], tid);
            stageF<K>(Bb + (long long)(t + 2) * 128, Bs[t & 1], tid);
        }
        MMF(af2, bfv2)
    }
#undef RDF
#undef WAITLF
#undef MMF

    if constexpr (EPI == 10) {
        if (swapped) {  // u (bx<6) or bS (bx==12)
            int rowb = by * 256 + wr * 128 + c15;
            int colb = bx * 256 + wc * 64 + (qq << 2);
#pragma unroll
            for (int m = 0; m < 8; ++m) {
#pragma unroll
                for (int n = 0; n < 4; ++n) {
                    int R = rowb + m * 16;
                    int C = colb + n * 16;
                    f32x4 a = acc[m][n];
                    if (C < 1536) {
                        f32x4 bb = *(const f32x4*)((const float*)p3 + C);
                        u16x4 o;
#pragma unroll
                        for (int i = 0; i < 4; ++i)
                            o[i] = f2b(silu(a[i] * 0.03125f + bb[i]));
                        *(u16x4*)((unsigned short*)p0 + (long long)R * 1536 + C) = o;
                    } else if (C < 3200) {  // bS
                        f32x4 bb = *(const f32x4*)((const float*)p3 + C);
                        u16x4 o;
#pragma unroll
                        for (int i = 0; i < 4; ++i)
                            o[i] = f2b(silu(a[i] * 0.03125f + bb[i]));
                        *(u16x4*)((unsigned short*)p2 + (long long)R * 128 + (C - 3072)) = o;
                    }
                }
            }
        } else {  // vT
            int rowb = by * 256 + wr * 128 + (qq << 2);
            int colb = bx * 256 + wc * 64 + c15;
#pragma unroll
            for (int m = 0; m < 8; ++m) {
#pragma unroll
                for (int n = 0; n < 4; ++n) {
                    int R = rowb + m * 16;
                    int C = colb + n * 16;  // 1536..3071
                    float bias = ((const float*)p3)[C];
                    f32x4 a = acc[m][n];
                    u16x4 o;
#pragma unroll
                    for (int i = 0; i < 4; ++i)
                        o[i] = f2b(silu(a[i] * 0.03125f + bias));
                    int bb2 = R >> 9, mm = R & 511;
                    *(u16x4*)((unsigned short*)p1 +
                              ((long long)bb2 * 1536 + (C - 1536)) * 512 + mm) = o;
                }
            }
        }
    } else {  // EPI == 3: out = acc/256 + o_b + x
        int rowb = by * 256 + wr * 128 + c15;
        int colb = bx * 256 + wc * 64 + (qq << 2);
#pragma unroll
        for (int m = 0; m < 8; ++m) {
#pragma unroll
            for (int n = 0; n < 4; ++n) {
                int R = rowb + m * 16;
                int C = colb + n * 16;
                f32x4 a = acc[m][n];
                long long idx = (long long)R * 768 + C;
                f32x4 xv = *(const f32x4*)((const float*)p2 + idx);
                f32x4 ob = *(const f32x4*)((const float*)p1 + C);
                f32x4 o;
#pragma unroll
                for (int i = 0; i < 4; ++i) o[i] = a[i] * 0.00390625f + ob[i] + xv[i];
                *(f32x4*)((float*)p0 + idx) = o;
            }
        }
    }
}

extern "C" void kernel_launch(void* const* d_in, const int* in_sizes, int n_in,
                              void* d_out, int out_size, void* d_ws, size_t ws_size,
                              hipStream_t stream) {
    const float* x     = (const float*)d_in[0];
    const float* ln_g  = (const float*)d_in[1];
    const float* ln_b  = (const float*)d_in[2];
    const float* uv_W  = (const float*)d_in[3];
    const float* uv_b  = (const float*)d_in[4];
    const float* g_qk  = (const float*)d_in[5];
    const float* b_qk  = (const float*)d_in[6];
    const float* w_rel = (const float*)d_in[7];
    const float* o_W   = (const float*)d_in[8];
    const float* o_b   = (const float*)d_in[9];
    float* out = (float*)d_out;

    char* ws = (char*)d_ws;
    size_t off = 0;
    auto alloc = [&](size_t bytes) {
        void* p = ws + off;
        off += (bytes + 255) & ~(size_t)255;
        return p;
    };
    // P (16.8MB) aliases the [xn8|uvWT8|bS] region (19.4MB), all dead by QK time.
    u8* xn8    = (u8*)alloc(16384ll * 768);       // fp8 LN out
    u8* uvWT8  = (u8*)alloc(3328ll * 768);        // fp8 x32, rows 3200+ = pad
    unsigned short* bS = (unsigned short*)alloc(16384ll * 128 * 2);
    u8* oWT8   = (u8*)alloc(768ll * 1536);        // fp8 x32
    unsigned short* u  = (unsigned short*)alloc(16384ll * 1536 * 2);
    unsigned short* vT = (unsigned short*)alloc(32ll * 1536 * 512 * 2);
    unsigned short* q  = (unsigned short*)alloc(32ll * 512 * 128 * 2);
    unsigned short* k  = (unsigned short*)alloc(32ll * 512 * 128 * 2);
    u8* gated8 = (u8*)alloc(16384ll * 1536);      // fp8 x8
    unsigned short* P = (unsigned short*)xn8;     // [32][512][512] bf16 alias

    k_convT8<<<dim3(100, 24), dim3(32, 8), 0, stream>>>(uv_W, uvWT8, 768, 3200, 32.0f);
    k_convT8<<<dim3(24, 48), dim3(32, 8), 0, stream>>>(o_W, oWT8, 1536, 768, 32.0f);
    k_ln<<<16384, 256, 0, stream>>>(x, ln_g, ln_b, xn8);
    // UV fp8: u | vT | bS   (N=3328 incl. pad; K=768 -> NT=6)
    kF<10, true, 6><<<dim3(13, 64), 512, 0, stream>>>(
        xn8, uvWT8, (void*)u, (void*)vT, (void*)bS, (const void*)uv_b);
    k_rope<<<16384, 128, 0, stream>>>(bS, g_qk, b_qk, q, k);
    // QK^T -> P (bf16)
    k_qk<<<dim3(4, 4, 32), 256, 0, stream>>>(q, k, w_rel, P);
    // PV bf16, gated -> fp8 x8   (K=512 -> NT=8)
    k_pv<8><<<dim3(6, 2, 32), 512, 0, stream>>>(
        P, vT, 512ll * 512, 1536ll * 512, gated8, u);
    // out fp8 = gated8 @ oWT8^T /256 + o_b + x   (K=1536 -> NT=12)
    kF<3, true, 12><<<dim3(3, 64), 512, 0, stream>>>(
        gated8, oWT8, (void*)out, (void*)o_b, (void*)x, nullptr);
}

// Round 11
// 283.986 us; speedup vs baseline: 2.8073x; 2.8073x over previous
//
#include <hip/hip_runtime.h>
#include <hip/hip_bf16.h>
#include <math.h>

typedef __bf16 bf16x8 __attribute__((ext_vector_type(8)));
typedef float f32x4 __attribute__((ext_vector_type(4)));
typedef unsigned short u16x4 __attribute__((ext_vector_type(4)));

#define AS1P const __attribute__((address_space(1))) void*
#define AS3P __attribute__((address_space(3))) void*

__device__ __forceinline__ float b2f(unsigned short h) {
    unsigned int u = ((unsigned int)h) << 16;
    return __builtin_bit_cast(float, u);
}
__device__ __forceinline__ unsigned short f2b(float f) {
    unsigned int u = __builtin_bit_cast(unsigned int, f);
    u += 0x7FFFu + ((u >> 16) & 1u);
    return (unsigned short)(u >> 16);
}
__device__ __forceinline__ float silu(float c) {
    return c * __builtin_amdgcn_rcpf(1.0f + __expf(-c));
}

// ---------------- tiled transpose + bf16 convert
__global__ __launch_bounds__(256) void k_convT(const float* __restrict__ src,
                                               unsigned short* __restrict__ dst,
                                               int R, int C) {
    __shared__ float tile[32][33];
    int tx = threadIdx.x, ty = threadIdx.y;
    int r0 = blockIdx.y << 5, c0 = blockIdx.x << 5;
#pragma unroll
    for (int i = 0; i < 4; ++i)
        tile[ty + 8 * i][tx] = src[(long long)(r0 + ty + 8 * i) * C + c0 + tx];
    __syncthreads();
#pragma unroll
    for (int i = 0; i < 4; ++i)
        dst[(long long)(c0 + ty + 8 * i) * R + r0 + tx] = f2b(tile[tx][ty + 8 * i]);
}

// ---------------- LayerNorm
__global__ __launch_bounds__(256) void k_ln(const float* __restrict__ x,
                                            const float* __restrict__ g,
                                            const float* __restrict__ b,
                                            unsigned short* __restrict__ xn) {
    int row = blockIdx.x;
    int t = threadIdx.x;
    const float* xr = x + (long long)row * 768;
    float v0 = xr[t], v1 = xr[t + 256], v2 = xr[t + 512];
    float s = v0 + v1 + v2;
    float q = v0 * v0 + v1 * v1 + v2 * v2;
#pragma unroll
    for (int off = 32; off > 0; off >>= 1) {
        s += __shfl_xor(s, off);
        q += __shfl_xor(q, off);
    }
    __shared__ float ss[4], sq[4];
    int w = t >> 6;
    if ((t & 63) == 0) { ss[w] = s; sq[w] = q; }
    __syncthreads();
    float S_ = ss[0] + ss[1] + ss[2] + ss[3];
    float Q_ = sq[0] + sq[1] + sq[2] + sq[3];
    float mu = S_ * (1.0f / 768.0f);
    float var = Q_ * (1.0f / 768.0f) - mu * mu;
    float rs = rsqrtf(var + 1e-5f);
    unsigned short* xo = xn + (long long)row * 768;
    xo[t]       = f2b((v0 - mu) * rs * g[t]       + b[t]);
    xo[t + 256] = f2b((v1 - mu) * rs * g[t + 256] + b[t + 256]);
    xo[t + 512] = f2b((v2 - mu) * rs * g[t + 512] + b[t + 512]);
}

// ---------------- RoPE + per-head affine
__global__ __launch_bounds__(128) void k_rope(const unsigned short* __restrict__ bS,
                                              const float* __restrict__ gqk,
                                              const float* __restrict__ bqk,
                                              unsigned short* __restrict__ q,
                                              unsigned short* __restrict__ k) {
    int row = blockIdx.x;
    int l = row & 511;
    int s = threadIdx.x;
    int j = s & 63;
    int partner = s ^ 64;
    float b0 = b2f(bS[(long long)row * 128 + s]);
    float bp = b2f(bS[(long long)row * 128 + partner]);
    float invf = __expf((float)j * -0.14391156831f);
    float th = (float)l * invf;
    float sn, cs;
    __sincosf(th, &sn, &cs);
    float sign = (s < 64) ? -1.0f : 1.0f;
    float preq  = b0 * gqk[s]           + bqk[s];
    float preqp = bp * gqk[partner]     + bqk[partner];
    q[(long long)row * 128 + s] = f2b(preq * cs + sign * preqp * sn);
    float prek  = b0 * gqk[128 + s]       + bqk[128 + s];
    float prekp = bp * gqk[128 + partner] + bqk[128 + partner];
    k[(long long)row * 128 + s] = f2b(prek * cs + sign * prekp * sn);
}

// ================= 128^2 2-phase kernel (QK only: P = relu^2(qk/L + bias))
// bz-inclusive chunked XCD swizzle: each XCD gets 4 contiguous batches.
__global__ __launch_bounds__(256) void k_qk(const unsigned short* __restrict__ A,
                                            const unsigned short* __restrict__ B,
                                            const float* __restrict__ wrel,
                                            unsigned short* __restrict__ P) {
    __shared__ __align__(16) unsigned short As[128 * 64];
    __shared__ __align__(16) unsigned short Bs[128 * 64];
    int t = threadIdx.x;
    int w = t >> 6, lane = t & 63;
    int wr = w >> 1, wc = w & 1;
    int bx = blockIdx.x, by = blockIdx.y, bz = blockIdx.z;
    {   // flat xyz swizzle (512 blocks, %8==0 -> bijective)
        int gx = gridDim.x, gy = gridDim.y;
        int nb = gx * gy * gridDim.z;
        int bid = (bz * gy + by) * gx + bx;
        int s = (bid & 7) * (nb >> 3) + (bid >> 3);
        bx = s % gx;
        by = (s / gx) % gy;
        bz = s / (gx * gy);
    }
    const unsigned short* Ab = A + (long long)bz * 512 * 128 + (long long)by * 128 * 128;
    const unsigned short* Bb = B + (long long)bz * 512 * 128 + (long long)bx * 128 * 128;

    f32x4 acc[4][4];
#pragma unroll
    for (int m = 0; m < 4; ++m)
#pragma unroll
        for (int n = 0; n < 4; ++n) acc[m][n] = (f32x4){0.f, 0.f, 0.f, 0.f};

    int rowA = (w << 3) + (lane >> 3);
    int colA = (lane & 7) << 3;

    for (int k0 = 0; k0 < 128; k0 += 64) {
#pragma unroll
        for (int i = 0; i < 4; ++i) {
            int r = (i << 5) + rowA;
            __builtin_amdgcn_global_load_lds(
                (AS1P)(Ab + (long long)r * 128 + k0 + colA),
                (AS3P)(&As[(i << 11) + (w << 9)]), 16, 0, 0);
            __builtin_amdgcn_global_load_lds(
                (AS1P)(Bb + (long long)r * 128 + k0 + colA),
                (AS3P)(&Bs[(i << 11) + (w << 9)]), 16, 0, 0);
        }
        __syncthreads();
#pragma unroll
        for (int ks = 0; ks < 2; ++ks) {
            bf16x8 af[4], bfr[4];
#pragma unroll
            for (int m = 0; m < 4; ++m)
                af[m] = *(const bf16x8*)&As[((wr << 6) + (m << 4) + (lane & 15)) * 64 +
                                            (ks << 5) + ((lane >> 4) << 3)];
#pragma unroll
            for (int n = 0; n < 4; ++n)
                bfr[n] = *(const bf16x8*)&Bs[((wc << 6) + (n << 4) + (lane & 15)) * 64 +
                                             (ks << 5) + ((lane >> 4) << 3)];
#pragma unroll
            for (int m = 0; m < 4; ++m)
#pragma unroll
                for (int n = 0; n < 4; ++n)
                    acc[m][n] = __builtin_amdgcn_mfma_f32_16x16x32_bf16(bfr[n], af[m],
                                                                        acc[m][n], 0, 0, 0);
        }
        __syncthreads();
    }

    int c15 = lane & 15, qq = lane >> 4;
    int rowb = (by << 7) + (wr << 6) + c15;
    int colb = (bx << 7) + (wc << 6) + (qq << 2);
#pragma unroll
    for (int m = 0; m < 4; ++m) {
#pragma unroll
        for (int n = 0; n < 4; ++n) {
            int grow = rowb + (m << 4);
            int gcol = colb + (n << 4);
            f32x4 a = acc[m][n];
            int base = gcol - grow + 511;
            u16x4 o;
#pragma unroll
            for (int i = 0; i < 4; ++i) {
                float val = a[i] * (1.0f / 512.0f) + wrel[base + i];
                val = fmaxf(val, 0.0f);
                o[i] = f2b(val * val);
            }
            *(u16x4*)(P + ((long long)(bz * 512 + grow)) * 512 + gcol) = o;
        }
    }
}

// ================= 256x256 8-phase kernel (R7-verified best): BK=64, 512 thr.
// LDS [buf][khalf][256][32]; phase p: ks=p>>1, mh=p&1; 16 MFMA per phase.
// Stage order: ph0->A-K1(t+1), ph1->B-K1(t+1), ph2->A-K0(t+2), ph3->B-K0(t+2).
// Waits: vmcnt(8) at ends of ph1/ph3 (tail 8->4->0). Granule swizzle g^=(row>>1)&3.
__device__ __forceinline__ bf16x8 ldsread(const unsigned short* p) {
    bf16x8 r;
    unsigned int off =
        (unsigned int)(unsigned long long)(__attribute__((address_space(3))) const void*)p;
    asm volatile("ds_read_b128 %0, %1" : "=v"(r) : "v"(off));
    return r;
}
// stage one half-tile: 256 rows x 32 cols (16KB), 512 threads x 2 loads.
__device__ __forceinline__ void stage_half(const unsigned short* __restrict__ g, int ldk,
                                           unsigned short* lds, int t) {
#pragma unroll
    for (int i = 0; i < 2; ++i) {
        int slot = t + (i << 9);
        int row = slot >> 2;
        int gs = (slot & 3) ^ ((slot >> 3) & 3);
        __builtin_amdgcn_global_load_lds(
            (AS1P)(g + (long long)row * ldk + (gs << 3)),
            (AS3P)(lds + slot * 8), 16, 0, 0);
    }
}

template <bool SWAP, int NT>
__device__ __forceinline__ void kloop8(const unsigned short* __restrict__ Ab,
                                       const unsigned short* __restrict__ Bb,
                                       unsigned short* As, unsigned short* Bs,
                                       f32x4 (&acc)[8][4], int tid,
                                       int wr, int wc, int c15, int qq, int gq) {
    constexpr int K = NT * 64;
    // prologue: tile0 all 4 halves + tile1 K0 halves
    stage_half(Ab, K, As + 0, tid);
    stage_half(Bb, K, Bs + 0, tid);
    stage_half(Ab + 32, K, As + 8192, tid);
    stage_half(Bb + 32, K, Bs + 8192, tid);
    stage_half(Ab + 64, K, As + 16384, tid);
    stage_half(Bb + 64, K, Bs + 16384, tid);
    asm volatile("s_waitcnt vmcnt(8)" ::: "memory");
    __builtin_amdgcn_s_barrier();

    bf16x8 bfr[4], af[4];
    for (int t = 0; t < NT; ++t) {
        const int b = t & 1;
        const unsigned short* A0 = As + b * 16384;
        const unsigned short* B0 = Bs + b * 16384;
#pragma unroll
        for (int p = 0; p < 4; ++p) {
            const int ks = p >> 1, mh = p & 1;
            const unsigned short* At = A0 + ks * 8192;
            const unsigned short* Bt = B0 + ks * 8192;
            if (mh == 0) {
#pragma unroll
                for (int n = 0; n < 4; ++n)
                    bfr[n] = ldsread(Bt + (wc * 64 + n * 16 + c15) * 32 + gq * 8);
            }
#pragma unroll
            for (int j = 0; j < 4; ++j)
                af[j] = ldsread(At + (wr * 128 + (mh * 4 + j) * 16 + c15) * 32 + gq * 8);
            if (p == 0) {
                if (t + 1 < NT)
                    stage_half(Ab + (t + 1) * 64 + 32, K,
                               As + (((t + 1) & 1) * 2 + 1) * 8192, tid);
            } else if (p == 1) {
                if (t + 1 < NT)
                    stage_half(Bb + (t + 1) * 64 + 32, K,
                               Bs + (((t + 1) & 1) * 2 + 1) * 8192, tid);
            } else if (p == 2) {
                if (t + 2 < NT)
                    stage_half(Ab + (t + 2) * 64, K, As + (b * 2) * 8192, tid);
            } else {
                if (t + 2 < NT)
                    stage_half(Bb + (t + 2) * 64, K, Bs + (b * 2) * 8192, tid);
            }
            __builtin_amdgcn_s_barrier();
            asm volatile("s_waitcnt lgkmcnt(0)" ::: "memory");
            __builtin_amdgcn_sched_barrier(0);
            __builtin_amdgcn_s_setprio(1);
#pragma unroll
            for (int j = 0; j < 4; ++j)
#pragma unroll
                for (int n = 0; n < 4; ++n) {
                    if constexpr (SWAP)
                        acc[mh * 4 + j][n] = __builtin_amdgcn_mfma_f32_16x16x32_bf16(
                            bfr[n], af[j], acc[mh * 4 + j][n], 0, 0, 0);
                    else
                        acc[mh * 4 + j][n] = __builtin_amdgcn_mfma_f32_16x16x32_bf16(
                            af[j], bfr[n], acc[mh * 4 + j][n], 0, 0, 0);
                }
            __builtin_amdgcn_s_setprio(0);
            if (p == 1) {
                if (t < NT - 1)
                    asm volatile("s_waitcnt vmcnt(8)" ::: "memory");
                else
                    asm volatile("s_waitcnt vmcnt(0)" ::: "memory");
            } else if (p == 3) {
                if (t < NT - 2)
                    asm volatile("s_waitcnt vmcnt(8)" ::: "memory");
                else if (t == NT - 2)
                    asm volatile("s_waitcnt vmcnt(4)" ::: "memory");
            }
            __builtin_amdgcn_sched_barrier(0);
            __builtin_amdgcn_s_barrier();
        }
    }
}

// EPI: 10 = UV merged (u | vT | bS by bx)   2 = gated(PV*u)   3 = out f32(+o_b+x)
// SWZ: 0 = none, 1 = xy chunked XCD swizzle, 2 = flat xyz chunked XCD swizzle
template <int EPI, int SWZ, int NT>
__global__ __launch_bounds__(512, 2) void k8(const unsigned short* __restrict__ A,
                                             const unsigned short* __restrict__ B,
                                             long long strideA, long long strideB,
                                             void* p0, void* p1, void* p2,
                                             const void* p3) {
    constexpr int K = NT * 64;
    __shared__ __align__(16) unsigned short As[2][2][256 * 32];
    __shared__ __align__(16) unsigned short Bs[2][2][256 * 32];
    int tid = threadIdx.x;
    int w = tid >> 6, lane = tid & 63;
    int wr = w >> 2, wc = w & 3;
    int c15 = lane & 15, qq = lane >> 4;
    int gq = qq ^ ((c15 >> 1) & 3);
    int bx = blockIdx.x, by = blockIdx.y, bz = blockIdx.z;
    if constexpr (SWZ == 1) {
        int gx = gridDim.x;
        int nb = gx * gridDim.y;
        int bid = by * gx + bx;
        int s = (bid & 7) * (nb >> 3) + (bid >> 3);
        bx = s % gx;
        by = s / gx;
    } else if constexpr (SWZ == 2) {
        int gx = gridDim.x, gy = gridDim.y;
        int nb = gx * gy * gridDim.z;
        int bid = (bz * gy + by) * gx + bx;
        int s = (bid & 7) * (nb >> 3) + (bid >> 3);
        bx = s % gx;
        by = (s / gx) % gy;
        bz = s / (gx * gy);
    }
    const unsigned short* Ab = A + bz * strideA + (long long)by * 256 * K;
    const unsigned short* Bb = B + bz * strideB + (long long)bx * 256 * K;

    f32x4 acc[8][4];
#pragma unroll
    for (int m = 0; m < 8; ++m)
#pragma unroll
        for (int n = 0; n < 4; ++n) acc[m][n] = (f32x4){0.f, 0.f, 0.f, 0.f};

    bool swapped = true;
    if constexpr (EPI == 10) {
        swapped = !(bx >= 6 && bx < 12);
        if (swapped)
            kloop8<true, NT>(Ab, Bb, &As[0][0][0], &Bs[0][0][0], acc, tid, wr, wc, c15, qq, gq);
        else
            kloop8<false, NT>(Ab, Bb, &As[0][0][0], &Bs[0][0][0], acc, tid, wr, wc, c15, qq, gq);
    } else {
        kloop8<true, NT>(Ab, Bb, &As[0][0][0], &Bs[0][0][0], acc, tid, wr, wc, c15, qq, gq);
    }

    if constexpr (EPI == 10) {
        if (swapped) {  // u (bx<6) or bS (bx==12): C^T frags -> row-major stores
            int rowb = by * 256 + wr * 128 + c15;
            int colb = bx * 256 + wc * 64 + (qq << 2);
#pragma unroll
            for (int m = 0; m < 8; ++m) {
#pragma unroll
                for (int n = 0; n < 4; ++n) {
                    int R = rowb + m * 16;
                    int C = colb + n * 16;
                    f32x4 a = acc[m][n];
                    if (C < 1536) {
                        f32x4 bb = *(const f32x4*)((const float*)p3 + C);
                        u16x4 o;
#pragma unroll
                        for (int i = 0; i < 4; ++i) o[i] = f2b(silu(a[i] + bb[i]));
                        *(u16x4*)((unsigned short*)p0 + (long long)R * 1536 + C) = o;
                    } else if (C < 3200) {  // bS
                        f32x4 bb = *(const f32x4*)((const float*)p3 + C);
                        u16x4 o;
#pragma unroll
                        for (int i = 0; i < 4; ++i) o[i] = f2b(silu(a[i] + bb[i]));
                        *(u16x4*)((unsigned short*)p2 + (long long)R * 128 + (C - 3072)) = o;
                    }
                }
            }
        } else {  // vT: thread holds 4 consecutive out-rows at one col
            int rowb = by * 256 + wr * 128 + (qq << 2);
            int colb = bx * 256 + wc * 64 + c15;
#pragma unroll
            for (int m = 0; m < 8; ++m) {
#pragma unroll
                for (int n = 0; n < 4; ++n) {
                    int R = rowb + m * 16;
                    int C = colb + n * 16;  // 1536..3071
                    float bias = ((const float*)p3)[C];
                    f32x4 a = acc[m][n];
                    u16x4 o;
#pragma unroll
                    for (int i = 0; i < 4; ++i) o[i] = f2b(silu(a[i] + bias));
                    int bb2 = R >> 9, mm = R & 511;
                    *(u16x4*)((unsigned short*)p1 +
                              ((long long)bb2 * 1536 + (C - 1536)) * 512 + mm) = o;
                }
            }
        }
    } else if constexpr (EPI == 2) {
        int rowb = by * 256 + wr * 128 + c15;
        int colb = bx * 256 + wc * 64 + (qq << 2);
#pragma unroll
        for (int m = 0; m < 8; ++m) {
#pragma unroll
            for (int n = 0; n < 4; ++n) {
                int R = rowb + m * 16;
                int C = colb + n * 16;
                f32x4 a = acc[m][n];
                long long idx = ((long long)(bz * 512 + R)) * 1536 + C;
                u16x4 uu = *(const u16x4*)((const unsigned short*)p1 + idx);
                u16x4 o;
#pragma unroll
                for (int i = 0; i < 4; ++i) o[i] = f2b(a[i] * b2f(uu[i]));
                *(u16x4*)((unsigned short*)p0 + idx) = o;
            }
        }
    } else {  // EPI == 3
        int rowb = by * 256 + wr * 128 + c15;
        int colb = bx * 256 + wc * 64 + (qq << 2);
#pragma unroll
        for (int m = 0; m < 8; ++m) {
#pragma unroll
            for (int n = 0; n < 4; ++n) {
                int R = rowb + m * 16;
                int C = colb + n * 16;
                f32x4 a = acc[m][n];
                long long idx = (long long)R * 768 + C;
                f32x4 xv = *(const f32x4*)((const float*)p2 + idx);
                f32x4 ob = *(const f32x4*)((const float*)p1 + C);
                f32x4 o;
#pragma unroll
                for (int i = 0; i < 4; ++i) o[i] = a[i] + ob[i] + xv[i];
                *(f32x4*)((float*)p0 + idx) = o;
            }
        }
    }
}

extern "C" void kernel_launch(void* const* d_in, const int* in_sizes, int n_in,
                              void* d_out, int out_size, void* d_ws, size_t ws_size,
                              hipStream_t stream) {
    const float* x     = (const float*)d_in[0];
    const float* ln_g  = (const float*)d_in[1];
    const float* ln_b  = (const float*)d_in[2];
    const float* uv_W  = (const float*)d_in[3];
    const float* uv_b  = (const float*)d_in[4];
    const float* g_qk  = (const float*)d_in[5];
    const float* b_qk  = (const float*)d_in[6];
    const float* w_rel = (const float*)d_in[7];
    const float* o_W   = (const float*)d_in[8];
    const float* o_b   = (const float*)d_in[9];
    float* out = (float*)d_out;

    char* ws = (char*)d_ws;
    size_t off = 0;
    auto alloc = [&](size_t bytes) {
        void* p = ws + off;
        off += (bytes + 255) & ~(size_t)255;
        return p;
    };
    unsigned short* uvWT = (unsigned short*)alloc(3328ll * 768 * 2);  // rows 3200+ = pad
    unsigned short* oWT  = (unsigned short*)alloc(768ll * 1536 * 2);
    unsigned short* xn   = (unsigned short*)alloc(16384ll * 768 * 2);
    unsigned short* u    = (unsigned short*)alloc(16384ll * 1536 * 2);
    unsigned short* vT   = (unsigned short*)alloc(32ll * 1536 * 512 * 2);
    unsigned short* bS   = (unsigned short*)alloc(16384ll * 128 * 2);
    unsigned short* q    = (unsigned short*)alloc(32ll * 512 * 128 * 2);
    unsigned short* k    = (unsigned short*)alloc(32ll * 512 * 128 * 2);
    unsigned short* P     = xn;  // alias: xn dead after UV kernel
    unsigned short* gated = u;   // alias: same-thread read-then-write

    k_convT<<<dim3(100, 24), dim3(32, 8), 0, stream>>>(uv_W, uvWT, 768, 3200);
    k_convT<<<dim3(24, 48), dim3(32, 8), 0, stream>>>(o_W, oWT, 1536, 768);
    k_ln<<<16384, 256, 0, stream>>>(x, ln_g, ln_b, xn);
    // UV merged: u | vT | bS   (N=3328 incl. 128 masked cols; K=768 -> NT=12)
    k8<10, 1, 12><<<dim3(13, 64), 512, 0, stream>>>(
        xn, uvWT, 0, 0, (void*)u, (void*)vT, (void*)bS, (const void*)uv_b);
    k_rope<<<16384, 128, 0, stream>>>(bS, g_qk, b_qk, q, k);
    // QK^T -> P (bz-chunked XCD swizzle inside)
    k_qk<<<dim3(4, 4, 32), 256, 0, stream>>>(q, k, w_rel, P);
    // PV gated by u   (K=512 -> NT=8; flat xyz XCD swizzle: 4 batches per XCD)
    k8<2, 2, 8><<<dim3(6, 2, 32), 512, 0, stream>>>(
        P, vT, 512ll * 512, 1536ll * 512, (void*)gated, (void*)u, nullptr, nullptr);
    // out = gated @ oWT^T + o_b + x   (K=1536 -> NT=24)
    k8<3, 1, 24><<<dim3(3, 64), 512, 0, stream>>>(
        gated, oWT, 0, 0, (void*)out, (void*)o_b, (void*)x, nullptr);
}